// Round 8
// baseline (173.069 us; speedup 1.0000x reference)
//
#include <hip/hip_runtime.h>
#include <hip/hip_cooperative_groups.h>
#include <math.h>

#define BATCH 8
#define NN 2048
#define FF 128

namespace cg = cooperative_groups;

typedef __attribute__((ext_vector_type(4))) float f32x4;
typedef _Float16 half8 __attribute__((ext_vector_type(8)));

__device__ __forceinline__ unsigned short h2u(_Float16 h) {
    return __builtin_bit_cast(unsigned short, h);
}

__device__ __forceinline__ void h_split(float f, unsigned short& hi, unsigned short& lo) {
    const _Float16 hh = (_Float16)f;
    hi = h2u(hh);
    lo = h2u((_Float16)(f - (float)hh));
}

// ======================= Phase A: pack + W-frag ==========================
// 256 blocks x 512. Each block packs 8 adj rows -> transposed bitmask
// amT[jw][i] via ballot. Blocks 0..7 additionally emit W as fp16 hi/lo
// B-frag planes (8 x 2048 = 16384 entries exactly; ks = fi>>12 in 0..3).
// R7 BUG WAS HERE: 16 blocks -> fi up to 32767, OOB read of W + Wf_lo clobber.
__device__ __forceinline__ void phaseA(int bx, int t,
                                       const int* __restrict__ adj,
                                       const float* __restrict__ W,
                                       unsigned short* __restrict__ Wf_hi,
                                       unsigned short* __restrict__ Wf_lo,
                                       unsigned* __restrict__ amT) {
    const int w = t >> 6, lane = t & 63;
    const int row = bx * 8 + w;
    const int* __restrict__ ar = adj + (size_t)row * NN;
    #pragma unroll 8
    for (int seg = 0; seg < 32; ++seg) {
        const unsigned long long m = __ballot(ar[seg * 64 + lane] != 0);
        if (lane == 0)  amT[(size_t)(seg * 2) * NN + row] = (unsigned)m;
        if (lane == 32) amT[(size_t)(seg * 2 + 1) * NN + row] = (unsigned)(m >> 32);
    }
    if (bx < 8) {
        #pragma unroll
        for (int e = 0; e < 4; ++e) {
            const int fi = bx * 2048 + e * 512 + t;   // 0..16383
            const int j = fi & 7, ln = (fi >> 3) & 63, nt = (fi >> 9) & 7, ks = fi >> 12;
            const int k = ks * 32 + (ln >> 4) * 8 + j;
            const int col = nt * 16 + (ln & 15);
            unsigned short hh, hl;
            h_split(W[k * FF + col], hh, hl);
            Wf_hi[fi] = hh;
            Wf_lo[fi] = hl;
        }
    }
}

// ======================= Phase B: h = x @ W ==============================
// 256 blocks x 512: block = 64 rows x 128 cols; wave = 16 rows x 64 cols.
// fp16-split MFMA (xh*Wh + xl*Wh + xh*Wl); h stored as one fp16 plane in
// B-frag layout; epilogue: factored exponentials Sg/S2g/Eg/E2g.
__device__ __forceinline__ void phaseB(int bx, int t,
                                       const float* __restrict__ x,
                                       const unsigned short* __restrict__ Wf_hi,
                                       const unsigned short* __restrict__ Wf_lo,
                                       const float* __restrict__ a_src,
                                       const float* __restrict__ a_dst,
                                       unsigned short* __restrict__ hF,
                                       float* __restrict__ Eg, float* __restrict__ E2g,
                                       float* __restrict__ Sg, float* __restrict__ S2g,
                                       float* __restrict__ sred, float* __restrict__ dred) {
    const int w = t >> 6, lane = t & 63;
    const int nl = lane & 15, quad = lane >> 4;
    const int mt = w >> 1, ch = w & 1;
    const int row0 = bx * 64;
    const int b = row0 >> 11, jloc0 = row0 & 2047;
    const int gr = row0 + mt * 16 + nl;

    f32x4 acc[4] = {{0.f,0.f,0.f,0.f},{0.f,0.f,0.f,0.f},{0.f,0.f,0.f,0.f},{0.f,0.f,0.f,0.f}};

    #pragma unroll
    for (int ks = 0; ks < 4; ++ks) {
        const float4 xa = *reinterpret_cast<const float4*>(&x[(size_t)gr * FF + ks * 32 + quad * 8]);
        const float4 xb = *reinterpret_cast<const float4*>(&x[(size_t)gr * FF + ks * 32 + quad * 8 + 4]);
        const float xv[8] = {xa.x, xa.y, xa.z, xa.w, xb.x, xb.y, xb.z, xb.w};
        half8 ah, al;
        #pragma unroll
        for (int i = 0; i < 8; ++i) {
            const _Float16 hh = (_Float16)xv[i];
            ah[i] = hh;
            al[i] = (_Float16)(xv[i] - (float)hh);
        }
        #pragma unroll
        for (int nt = 0; nt < 4; ++nt) {
            const int gnt = ch * 4 + nt;
            const int bo = ((ks * 8 + gnt) * 64 + lane) * 8;
            const half8 bh = *reinterpret_cast<const half8*>(&Wf_hi[bo]);
            const half8 bl = *reinterpret_cast<const half8*>(&Wf_lo[bo]);
            acc[nt] = __builtin_amdgcn_mfma_f32_16x16x32_f16(ah, bh, acc[nt], 0, 0, 0);
            acc[nt] = __builtin_amdgcn_mfma_f32_16x16x32_f16(al, bh, acc[nt], 0, 0, 0);
            acc[nt] = __builtin_amdgcn_mfma_f32_16x16x32_f16(ah, bl, acc[nt], 0, 0, 0);
        }
    }

    const int jloc = jloc0 + mt * 16 + quad * 4;
    const int jg = jloc >> 3, u0 = jloc & 7;
    #pragma unroll
    for (int nt = 0; nt < 4; ++nt) {
        const int gnt = ch * 4 + nt;
        ushort4 hv;
        hv.x = h2u((_Float16)acc[nt][0]);
        hv.y = h2u((_Float16)acc[nt][1]);
        hv.z = h2u((_Float16)acc[nt][2]);
        hv.w = h2u((_Float16)acc[nt][3]);
        *reinterpret_cast<ushort4*>(&hF[(size_t)b * 262144 + gnt * 32768 + jg * 128 + nl * 8 + u0]) = hv;
    }

    float as[4], ad[4];
    #pragma unroll
    for (int nt = 0; nt < 4; ++nt) {
        const int col = ch * 64 + nt * 16 + nl;
        as[nt] = a_src[col];
        ad[nt] = a_dst[col];
    }
    #pragma unroll
    for (int r = 0; r < 4; ++r) {
        float sp = acc[0][r] * as[0] + acc[1][r] * as[1] + acc[2][r] * as[2] + acc[3][r] * as[3];
        float dp = acc[0][r] * ad[0] + acc[1][r] * ad[1] + acc[2][r] * ad[2] + acc[3][r] * ad[3];
        #pragma unroll
        for (int off = 8; off >= 1; off >>= 1) {
            sp += __shfl_xor(sp, off, 16);
            dp += __shfl_xor(dp, off, 16);
        }
        if (nl == 0) {
            sred[ch * 64 + mt * 16 + quad * 4 + r] = sp;
            dred[ch * 64 + mt * 16 + quad * 4 + r] = dp;
        }
    }
    __syncthreads();
    if (t < 64) {
        const float sp = sred[t] + sred[64 + t];
        const float dp = dred[t] + dred[64 + t];
        const int row = row0 + t;
        Sg[row]  = __expf(sp - 2.f);
        S2g[row] = __expf(0.2f * sp - 2.f);
        Eg[row]  = __expf(dp - 2.f);
        E2g[row] = __expf(0.2f * dp - 2.f);
    }
}

// ======================= Phase C: attn + PV ==============================
// 256 blocks x 512: b = bx>>5, i0 = (bx&31)*64. p = mask ? max(Si*Ej,S2i*E2j)
// : 0; single fp16 p plane -> f16 MFMA vs single-plane h; ones-column MFMA
// gives row sums (normalizes quantized p exactly).
__device__ __forceinline__ void phaseC(int bx, int t,
                                       const unsigned short* __restrict__ hF,
                                       const unsigned* __restrict__ amT,
                                       const float* __restrict__ Eg, const float* __restrict__ E2g,
                                       const float* __restrict__ Sg, const float* __restrict__ S2g,
                                       float* __restrict__ out,
                                       float* __restrict__ E_l, float* __restrict__ E2_l,
                                       unsigned* __restrict__ am_l, unsigned short* __restrict__ pA) {
    const int b = bx >> 5;
    const int i0 = (bx & 31) * 64;
    const int w = t >> 6, lane = t & 63;
    const int nl = lane & 15, quad = lane >> 4;

    *reinterpret_cast<float4*>(&E_l[t * 4])  = *reinterpret_cast<const float4*>(&Eg[(size_t)b * NN + t * 4]);
    *reinterpret_cast<float4*>(&E2_l[t * 4]) = *reinterpret_cast<const float4*>(&E2g[(size_t)b * NN + t * 4]);
    #pragma unroll
    for (int k = 0; k < 8; ++k) {
        const int idx = k * 512 + t;
        am_l[idx] = amT[(size_t)(idx >> 6) * NN + i0 + (idx & 63)];
    }
    __syncthreads();

    const int rp = t >> 4, jw4 = t & 15;
    const int ra = rp * 2, rb = ra + 1;
    const float Sa  = Sg[(size_t)b * NN + i0 + ra];
    const float S2a = S2g[(size_t)b * NN + i0 + ra];
    const float Sb  = Sg[(size_t)b * NN + i0 + rb];
    const float S2b = S2g[(size_t)b * NN + i0 + rb];
    const int bitb = (jw4 & 7) * 4;
    const int pwo = ra * 72 + jw4 * 4;

    const int mtp = w & 1, ntp = w >> 1;
    const unsigned short* __restrict__ hFb = hF + (size_t)b * 262144;
    int bofs[2], aofs[2];
    #pragma unroll
    for (int nn = 0; nn < 2; ++nn) bofs[nn] = (ntp + nn * 4) * 32768 + quad * 128 + nl * 8;
    #pragma unroll
    for (int mm = 0; mm < 2; ++mm) aofs[mm] = ((mtp + mm * 2) * 16 + nl) * 72 + quad * 8;

    f32x4 acc[2][2] = {{{0.f,0.f,0.f,0.f},{0.f,0.f,0.f,0.f}},{{0.f,0.f,0.f,0.f},{0.f,0.f,0.f,0.f}}};
    f32x4 lac[2] = {{0.f,0.f,0.f,0.f},{0.f,0.f,0.f,0.f}};
    half8 ones;
    #pragma unroll
    for (int i = 0; i < 8; ++i) ones[i] = (_Float16)1.f;

    for (int tt = 0; tt < 32; ++tt) {
        const int jt = tt * 64;
        const int buf = tt & 1;
        const int jofs = jt * 16;

        half8 bfr[2][2];
        #pragma unroll
        for (int nn = 0; nn < 2; ++nn) {
            bfr[nn][0] = *reinterpret_cast<const half8*>(hFb + bofs[nn] + jofs);
            bfr[nn][1] = *reinterpret_cast<const half8*>(hFb + bofs[nn] + jofs + 512);
        }

        {
            const int jb = jt + jw4 * 4;
            const float4 ej4  = *reinterpret_cast<const float4*>(&E_l[jb]);
            const float4 e2j4 = *reinterpret_cast<const float4*>(&E2_l[jb]);
            const uint2 mw = *reinterpret_cast<const uint2*>(&am_l[(tt * 2 + (jw4 >> 3)) * 64 + ra]);
            const float ejA[4]  = {ej4.x, ej4.y, ej4.z, ej4.w};
            const float e2jA[4] = {e2j4.x, e2j4.y, e2j4.z, e2j4.w};
            ushort4 ha, hb;
            #pragma unroll
            for (int jj = 0; jj < 4; ++jj) {
                const float ua = fmaxf(Sa * ejA[jj], S2a * e2jA[jj]);
                const float ub = fmaxf(Sb * ejA[jj], S2b * e2jA[jj]);
                const float pa = ((mw.x >> (bitb + jj)) & 1u) ? ua : 0.f;
                const float pb = ((mw.y >> (bitb + jj)) & 1u) ? ub : 0.f;
                ((unsigned short*)&ha)[jj] = h2u((_Float16)pa);
                ((unsigned short*)&hb)[jj] = h2u((_Float16)pb);
            }
            *reinterpret_cast<ushort4*>(&pA[buf * 4608 + pwo]) = ha;
            *reinterpret_cast<ushort4*>(&pA[buf * 4608 + pwo + 72]) = hb;
        }

        __syncthreads();

        half8 afr[2][2];
        #pragma unroll
        for (int mm = 0; mm < 2; ++mm) {
            afr[mm][0] = *reinterpret_cast<const half8*>(&pA[buf * 4608 + aofs[mm]]);
            afr[mm][1] = *reinterpret_cast<const half8*>(&pA[buf * 4608 + aofs[mm] + 32]);
        }
        #pragma unroll
        for (int mm = 0; mm < 2; ++mm) {
            #pragma unroll
            for (int kh = 0; kh < 2; ++kh) {
                lac[mm] = __builtin_amdgcn_mfma_f32_16x16x32_f16(afr[mm][kh], ones, lac[mm], 0, 0, 0);
                acc[mm][0] = __builtin_amdgcn_mfma_f32_16x16x32_f16(afr[mm][kh], bfr[0][kh], acc[mm][0], 0, 0, 0);
                acc[mm][1] = __builtin_amdgcn_mfma_f32_16x16x32_f16(afr[mm][kh], bfr[1][kh], acc[mm][1], 0, 0, 0);
            }
        }
    }

    #pragma unroll
    for (int mm = 0; mm < 2; ++mm) {
        const int row = i0 + (mtp + mm * 2) * 16 + quad * 4;
        #pragma unroll
        for (int r = 0; r < 4; ++r) {
            const float l = lac[mm][r];
            const float inv = (l > 0.f) ? 1.f / l : 0.f;
            #pragma unroll
            for (int nn = 0; nn < 2; ++nn) {
                const int col = (ntp + nn * 4) * 16 + nl;
                out[((size_t)b * NN + row + r) * FF + col] = acc[mm][nn][r] * inv;
            }
        }
    }
}

// ---------------------------------------------------------------------------
// Fused cooperative kernel (preferred): one dispatch, two grid syncs.
// ---------------------------------------------------------------------------
__global__ __launch_bounds__(512, 2) void k_fused(
        const float* __restrict__ x, const int* __restrict__ adj,
        const float* __restrict__ W, const float* __restrict__ a_src,
        const float* __restrict__ a_dst,
        unsigned short* __restrict__ Wf_hi, unsigned short* __restrict__ Wf_lo,
        unsigned short* __restrict__ hF,
        float* __restrict__ Eg, float* __restrict__ E2g,
        float* __restrict__ Sg, float* __restrict__ S2g,
        unsigned* __restrict__ amT, float* __restrict__ out) {
    __shared__ float E_l[NN];
    __shared__ float E2_l[NN];
    __shared__ unsigned am_l[64 * 64];
    __shared__ unsigned short pA[2 * 64 * 72];
    __shared__ float sred[2 * 64];
    __shared__ float dred[2 * 64];

    cg::grid_group grid = cg::this_grid();
    const int bx = blockIdx.x, t = threadIdx.x;

    phaseA(bx, t, adj, W, Wf_hi, Wf_lo, amT);
    grid.sync();
    phaseB(bx, t, x, Wf_hi, Wf_lo, a_src, a_dst, hF, Eg, E2g, Sg, S2g, sred, dred);
    grid.sync();
    phaseC(bx, t, hF, amT, Eg, E2g, Sg, S2g, out, E_l, E2_l, am_l, pA);
}

// ---------------------------------------------------------------------------
// Fallback path: identical phases as three ordinary kernels.
// ---------------------------------------------------------------------------
__global__ __launch_bounds__(512) void k_pA(const int* __restrict__ adj,
                                            const float* __restrict__ W,
                                            unsigned short* __restrict__ Wf_hi,
                                            unsigned short* __restrict__ Wf_lo,
                                            unsigned* __restrict__ amT) {
    phaseA(blockIdx.x, threadIdx.x, adj, W, Wf_hi, Wf_lo, amT);
}

__global__ __launch_bounds__(512, 2) void k_pB(const float* __restrict__ x,
                                               const unsigned short* __restrict__ Wf_hi,
                                               const unsigned short* __restrict__ Wf_lo,
                                               const float* __restrict__ a_src,
                                               const float* __restrict__ a_dst,
                                               unsigned short* __restrict__ hF,
                                               float* __restrict__ Eg, float* __restrict__ E2g,
                                               float* __restrict__ Sg, float* __restrict__ S2g) {
    __shared__ float sred[2 * 64];
    __shared__ float dred[2 * 64];
    phaseB(blockIdx.x, threadIdx.x, x, Wf_hi, Wf_lo, a_src, a_dst, hF, Eg, E2g, Sg, S2g, sred, dred);
}

__global__ __launch_bounds__(512, 2) void k_pC(const unsigned short* __restrict__ hF,
                                               const unsigned* __restrict__ amT,
                                               const float* __restrict__ Eg, const float* __restrict__ E2g,
                                               const float* __restrict__ Sg, const float* __restrict__ S2g,
                                               float* __restrict__ out) {
    __shared__ float E_l[NN];
    __shared__ float E2_l[NN];
    __shared__ unsigned am_l[64 * 64];
    __shared__ unsigned short pA[2 * 64 * 72];
    phaseC(blockIdx.x, threadIdx.x, hF, amT, Eg, E2g, Sg, S2g, out, E_l, E2_l, am_l, pA);
}

extern "C" void kernel_launch(void* const* d_in, const int* in_sizes, int n_in,
                              void* d_out, int out_size, void* d_ws, size_t ws_size,
                              hipStream_t stream) {
    const float* x     = (const float*)d_in[0];
    const int*   adj   = (const int*)d_in[1];
    const float* W     = (const float*)d_in[2];
    const float* a_src = (const float*)d_in[3];
    const float* a_dst = (const float*)d_in[4];
    float* out = (float*)d_out;

    unsigned short* hF    = (unsigned short*)d_ws;        // 4 MB
    unsigned short* Wf_hi = hF + 2097152;                 // 32 KB
    unsigned short* Wf_lo = Wf_hi + 16384;                // 32 KB
    float* Eg  = (float*)(Wf_lo + 16384);                 // 64 KB
    float* E2g = Eg + 16384;                              // 64 KB
    float* Sg  = E2g + 16384;                             // 64 KB
    float* S2g = Sg + 16384;                              // 64 KB
    unsigned* amT = (unsigned*)(S2g + 16384);             // 512 KB

    void* args[] = {(void*)&x, (void*)&adj, (void*)&W, (void*)&a_src, (void*)&a_dst,
                    (void*)&Wf_hi, (void*)&Wf_lo, (void*)&hF,
                    (void*)&Eg, (void*)&E2g, (void*)&Sg, (void*)&S2g,
                    (void*)&amT, (void*)&out};
    hipError_t err = hipLaunchCooperativeKernel((const void*)k_fused, dim3(256), dim3(512),
                                                args, 0, stream);
    if (err != hipSuccess) {
        // Cooperative launch unavailable (e.g., under graph capture) -> same
        // phases as three ordinary kernels.
        k_pA<<<256, 512, 0, stream>>>(adj, W, Wf_hi, Wf_lo, amT);
        k_pB<<<256, 512, 0, stream>>>(x, Wf_hi, Wf_lo, a_src, a_dst, hF, Eg, E2g, Sg, S2g);
        k_pC<<<256, 512, 0, stream>>>(hF, amT, Eg, E2g, Sg, S2g, out);
    }
}

// Round 9
// 117.626 us; speedup vs baseline: 1.4713x; 1.4713x over previous
//
#include <hip/hip_runtime.h>
#include <math.h>

#define BATCH 8
#define NN 2048
#define FF 128

typedef __attribute__((ext_vector_type(4))) float f32x4;
typedef _Float16 half8 __attribute__((ext_vector_type(8)));

__device__ __forceinline__ unsigned short h2u(_Float16 h) {
    return __builtin_bit_cast(unsigned short, h);
}

__device__ __forceinline__ void h_split(float f, unsigned short& hi, unsigned short& lo) {
    const _Float16 hh = (_Float16)f;
    hi = h2u(hh);
    lo = h2u((_Float16)(f - (float)hh));
}

// ---------------------------------------------------------------------------
// k_prep: blocks 0..511: adj -> transposed bitmask amT[jw][i], 4 rows/block
//         (2 blocks/CU, latency-pipelined ballots).
//         blocks 512..519: W -> fp16 hi/lo B-frag planes (8*2048 = 16384 exact).
// ---------------------------------------------------------------------------
__global__ __launch_bounds__(256) void k_prep(const int* __restrict__ adj,
                                              const float* __restrict__ W,
                                              unsigned short* __restrict__ Wf_hi,
                                              unsigned short* __restrict__ Wf_lo,
                                              unsigned* __restrict__ amT) {
    const int t = threadIdx.x;
    const int bx = blockIdx.x;
    if (bx < 512) {
        const int w = t >> 6, lane = t & 63;
        const int row = bx * 4 + w;
        const int* __restrict__ ar = adj + (size_t)row * NN;
        #pragma unroll 8
        for (int seg = 0; seg < 32; ++seg) {
            const unsigned long long m = __ballot(ar[seg * 64 + lane] != 0);
            if (lane == 0)  amT[(size_t)(seg * 2) * NN + row] = (unsigned)m;
            if (lane == 32) amT[(size_t)(seg * 2 + 1) * NN + row] = (unsigned)(m >> 32);
        }
    } else {
        #pragma unroll
        for (int e = 0; e < 8; ++e) {
            const int fi = (bx - 512) * 2048 + e * 256 + t;   // 0..16383
            const int j = fi & 7, ln = (fi >> 3) & 63, nt = (fi >> 9) & 7, ks = fi >> 12;
            const int k = ks * 32 + (ln >> 4) * 8 + j;
            const int col = nt * 16 + (ln & 15);
            unsigned short hh, hl;
            h_split(W[k * FF + col], hh, hl);
            Wf_hi[fi] = hh;
            Wf_lo[fi] = hl;
        }
    }
}

// ---------------------------------------------------------------------------
// k_h: h = x@W via fp16-split MFMA. 1024 blocks x 256 thr = 4 blocks/CU:
// block = 16 rows x 128 cols; wave = 16 rows x 32 cols (2 ntiles); A-frags
// 4x duplicated across waves (L1-hit). h stored as one fp16 plane in B-frag
// layout; epilogue: factored exponentials Sg/S2g/Eg/E2g.
// ---------------------------------------------------------------------------
__global__ __launch_bounds__(256) void k_h(const float* __restrict__ x,
                                           const unsigned short* __restrict__ Wf_hi,
                                           const unsigned short* __restrict__ Wf_lo,
                                           const float* __restrict__ a_src,
                                           const float* __restrict__ a_dst,
                                           unsigned short* __restrict__ hF,
                                           float* __restrict__ Eg,  float* __restrict__ E2g,
                                           float* __restrict__ Sg,  float* __restrict__ S2g) {
    __shared__ float sred[4 * 16];
    __shared__ float dred[4 * 16];

    const int t = threadIdx.x;
    const int w = t >> 6, lane = t & 63;
    const int nl = lane & 15, quad = lane >> 4;
    const int row0 = blockIdx.x * 16;
    const int b = row0 >> 11, jloc0 = row0 & 2047;
    const int gr = row0 + nl;
    const int nt0 = w * 2;  // wave's ntiles: nt0, nt0+1

    f32x4 acc[2] = {{0.f,0.f,0.f,0.f},{0.f,0.f,0.f,0.f}};

    #pragma unroll
    for (int ks = 0; ks < 4; ++ks) {
        const float4 xa = *reinterpret_cast<const float4*>(&x[(size_t)gr * FF + ks * 32 + quad * 8]);
        const float4 xb = *reinterpret_cast<const float4*>(&x[(size_t)gr * FF + ks * 32 + quad * 8 + 4]);
        const float xv[8] = {xa.x, xa.y, xa.z, xa.w, xb.x, xb.y, xb.z, xb.w};
        half8 ah, al;
        #pragma unroll
        for (int i = 0; i < 8; ++i) {
            const _Float16 hh = (_Float16)xv[i];
            ah[i] = hh;
            al[i] = (_Float16)(xv[i] - (float)hh);
        }
        #pragma unroll
        for (int nn = 0; nn < 2; ++nn) {
            const int bo = ((ks * 8 + nt0 + nn) * 64 + lane) * 8;
            const half8 bh = *reinterpret_cast<const half8*>(&Wf_hi[bo]);
            const half8 bl = *reinterpret_cast<const half8*>(&Wf_lo[bo]);
            acc[nn] = __builtin_amdgcn_mfma_f32_16x16x32_f16(ah, bh, acc[nn], 0, 0, 0);
            acc[nn] = __builtin_amdgcn_mfma_f32_16x16x32_f16(al, bh, acc[nn], 0, 0, 0);
            acc[nn] = __builtin_amdgcn_mfma_f32_16x16x32_f16(ah, bl, acc[nn], 0, 0, 0);
        }
    }

    // ---- h store: fp16 plane, B-frag layout [b][nt][jg][n][u] ----
    const int jloc = jloc0 + quad * 4;
    const int jg = jloc >> 3, u0 = jloc & 7;   // u0 in {0,4}
    #pragma unroll
    for (int nn = 0; nn < 2; ++nn) {
        ushort4 hv;
        hv.x = h2u((_Float16)acc[nn][0]);
        hv.y = h2u((_Float16)acc[nn][1]);
        hv.z = h2u((_Float16)acc[nn][2]);
        hv.w = h2u((_Float16)acc[nn][3]);
        *reinterpret_cast<ushort4*>(&hF[(size_t)b * 262144 + (nt0 + nn) * 32768 + jg * 128 + nl * 8 + u0]) = hv;
    }

    // ---- s_src / s_dst partials over this wave's 32 cols ----
    float as[2], ad[2];
    #pragma unroll
    for (int nn = 0; nn < 2; ++nn) {
        const int col = (nt0 + nn) * 16 + nl;
        as[nn] = a_src[col];
        ad[nn] = a_dst[col];
    }
    #pragma unroll
    for (int r = 0; r < 4; ++r) {
        float sp = acc[0][r] * as[0] + acc[1][r] * as[1];
        float dp = acc[0][r] * ad[0] + acc[1][r] * ad[1];
        #pragma unroll
        for (int off = 8; off >= 1; off >>= 1) {
            sp += __shfl_xor(sp, off, 16);
            dp += __shfl_xor(dp, off, 16);
        }
        if (nl == 0) {
            sred[w * 16 + quad * 4 + r] = sp;
            dred[w * 16 + quad * 4 + r] = dp;
        }
    }
    __syncthreads();
    if (t < 16) {
        const float sp = sred[t] + sred[16 + t] + sred[32 + t] + sred[48 + t];
        const float dp = dred[t] + dred[16 + t] + dred[32 + t] + dred[48 + t];
        const int row = row0 + t;
        Sg[row]  = __expf(sp - 2.f);
        S2g[row] = __expf(0.2f * sp - 2.f);
        Eg[row]  = __expf(dp - 2.f);
        E2g[row] = __expf(0.2f * dp - 2.f);
    }
}

// ---------------------------------------------------------------------------
// k_attn: p = mask ? max(Si*Ej, S2i*E2j) : 0  (= exp(lrelu(si+sj) - 4)).
// grid (32, 8, 2): bz = j-half -> 512 blocks x 512 thr = 2 blocks/CU,
// 4 waves/SIMD (2x latency hiding vs R6). Each block: 64 rows x 128 cols x
// 1024 j (16 tiles of 64). Writes UNNORMALIZED PV partials P[jh] + row-sum
// partials L[jh] (ones-column MFMA); k_comb normalizes.
// LDS ~34 KB: E 4K + E2 4K + am 8K + pA 18K.
// ---------------------------------------------------------------------------
__global__ __launch_bounds__(512, 4) void k_attn(const unsigned short* __restrict__ hF,
                                                 const unsigned* __restrict__ amT,
                                                 const float* __restrict__ Eg,
                                                 const float* __restrict__ E2g,
                                                 const float* __restrict__ Sg,
                                                 const float* __restrict__ S2g,
                                                 float* __restrict__ P,
                                                 float* __restrict__ L) {
    __shared__ float E_l[1024];                  // 4 KB (this j-half)
    __shared__ float E2_l[1024];                 // 4 KB
    __shared__ unsigned am_l[32 * 64];           // 8 KB  [jw2][row]
    __shared__ unsigned short pA[2 * 64 * 72];   // 18 KB

    const int t = threadIdx.x;
    const int b = blockIdx.y;
    const int i0 = blockIdx.x * 64;
    const int jh = blockIdx.z;
    const int jbase = jh * 1024;

    // ---- stage E/E2 half-row, half mask ----
    *reinterpret_cast<float2*>(&E_l[t * 2])  = *reinterpret_cast<const float2*>(&Eg[(size_t)b * NN + jbase + t * 2]);
    *reinterpret_cast<float2*>(&E2_l[t * 2]) = *reinterpret_cast<const float2*>(&E2g[(size_t)b * NN + jbase + t * 2]);
    #pragma unroll
    for (int k = 0; k < 4; ++k) {
        const int idx = k * 512 + t;             // 0..2047 = jw2(32) x row(64)
        am_l[idx] = amT[(size_t)(jh * 32 + (idx >> 6)) * NN + i0 + (idx & 63)];
    }
    __syncthreads();

    // ---- p-gen ids: thread = rows {2rp, 2rp+1} x 4 j ----
    const int rp = t >> 4, jw4 = t & 15;
    const int ra = rp * 2, rb = ra + 1;
    const float Sa  = Sg[(size_t)b * NN + i0 + ra];
    const float S2a = S2g[(size_t)b * NN + i0 + ra];
    const float Sb  = Sg[(size_t)b * NN + i0 + rb];
    const float S2b = S2g[(size_t)b * NN + i0 + rb];
    const int bitb = (jw4 & 7) * 4;
    const int pwo = ra * 72 + jw4 * 4;

    // ---- MFMA ids: wave = mtiles {mtp, mtp+2} x ntiles {ntp, ntp+4} ----
    const int w = t >> 6, lane = t & 63;
    const int nl = lane & 15, quad = lane >> 4;
    const int mtp = w & 1, ntp = w >> 1;
    const unsigned short* __restrict__ hFb = hF + (size_t)b * 262144;
    int bofs[2], aofs[2];
    #pragma unroll
    for (int nn = 0; nn < 2; ++nn) bofs[nn] = (ntp + nn * 4) * 32768 + (jbase + quad * 8) * 16 + nl * 8;
    #pragma unroll
    for (int mm = 0; mm < 2; ++mm) aofs[mm] = ((mtp + mm * 2) * 16 + nl) * 72 + quad * 8;

    f32x4 acc[2][2] = {{{0.f,0.f,0.f,0.f},{0.f,0.f,0.f,0.f}},{{0.f,0.f,0.f,0.f},{0.f,0.f,0.f,0.f}}};
    f32x4 lac[2] = {{0.f,0.f,0.f,0.f},{0.f,0.f,0.f,0.f}};
    half8 ones;
    #pragma unroll
    for (int i = 0; i < 8; ++i) ones[i] = (_Float16)1.f;

    for (int tt = 0; tt < 16; ++tt) {
        const int buf = tt & 1;
        const int jofs = tt * 1024;              // 64 j * 16 ushort per j-group

        half8 bfr[2][2];
        #pragma unroll
        for (int nn = 0; nn < 2; ++nn) {
            bfr[nn][0] = *reinterpret_cast<const half8*>(hFb + bofs[nn] + jofs);
            bfr[nn][1] = *reinterpret_cast<const half8*>(hFb + bofs[nn] + jofs + 512);
        }

        // ---- p-gen: 2 rows x 4 j ----
        {
            const int jb = tt * 64 + jw4 * 4;    // local j in this half
            const float4 ej4  = *reinterpret_cast<const float4*>(&E_l[jb]);
            const float4 e2j4 = *reinterpret_cast<const float4*>(&E2_l[jb]);
            const uint2 mw = *reinterpret_cast<const uint2*>(&am_l[(tt * 2 + (jw4 >> 3)) * 64 + ra]);
            const float ejA[4]  = {ej4.x, ej4.y, ej4.z, ej4.w};
            const float e2jA[4] = {e2j4.x, e2j4.y, e2j4.z, e2j4.w};
            ushort4 ha, hb;
            #pragma unroll
            for (int jj = 0; jj < 4; ++jj) {
                const float ua = fmaxf(Sa * ejA[jj], S2a * e2jA[jj]);
                const float ub = fmaxf(Sb * ejA[jj], S2b * e2jA[jj]);
                const float pa = ((mw.x >> (bitb + jj)) & 1u) ? ua : 0.f;
                const float pb = ((mw.y >> (bitb + jj)) & 1u) ? ub : 0.f;
                ((unsigned short*)&ha)[jj] = h2u((_Float16)pa);
                ((unsigned short*)&hb)[jj] = h2u((_Float16)pb);
            }
            *reinterpret_cast<ushort4*>(&pA[buf * 4608 + pwo]) = ha;
            *reinterpret_cast<ushort4*>(&pA[buf * 4608 + pwo + 72]) = hb;
        }

        __syncthreads();

        half8 afr[2][2];
        #pragma unroll
        for (int mm = 0; mm < 2; ++mm) {
            afr[mm][0] = *reinterpret_cast<const half8*>(&pA[buf * 4608 + aofs[mm]]);
            afr[mm][1] = *reinterpret_cast<const half8*>(&pA[buf * 4608 + aofs[mm] + 32]);
        }
        #pragma unroll
        for (int mm = 0; mm < 2; ++mm) {
            #pragma unroll
            for (int kh = 0; kh < 2; ++kh) {
                lac[mm] = __builtin_amdgcn_mfma_f32_16x16x32_f16(afr[mm][kh], ones, lac[mm], 0, 0, 0);
                acc[mm][0] = __builtin_amdgcn_mfma_f32_16x16x32_f16(afr[mm][kh], bfr[0][kh], acc[mm][0], 0, 0, 0);
                acc[mm][1] = __builtin_amdgcn_mfma_f32_16x16x32_f16(afr[mm][kh], bfr[1][kh], acc[mm][1], 0, 0, 0);
            }
        }
    }

    // ---- write unnormalized partials: C/D layout col=lane&15, row=quad*4+reg
    float* __restrict__ Pb = P + ((size_t)jh * BATCH + b) * 262144;
    float* __restrict__ Lb = L + ((size_t)jh * BATCH + b) * 2048;
    #pragma unroll
    for (int mm = 0; mm < 2; ++mm) {
        const int lrow = (mtp + mm * 2) * 16 + quad * 4;
        #pragma unroll
        for (int r = 0; r < 4; ++r) {
            #pragma unroll
            for (int nn = 0; nn < 2; ++nn) {
                const int col = (ntp + nn * 4) * 16 + nl;
                Pb[(size_t)(i0 + lrow + r) * FF + col] = acc[mm][nn][r];
            }
            if (nl == 0 && ntp == 0) Lb[i0 + lrow + r] = lac[mm][r];
        }
    }
}

// ---------------------------------------------------------------------------
// k_comb: out = (P0 + P1) / (L0 + L1); zero rows (no neighbors) -> 0.
// 1024 blocks x 256 thr; thread = 2 float4.
// ---------------------------------------------------------------------------
__global__ __launch_bounds__(256) void k_comb(const float* __restrict__ P,
                                              const float* __restrict__ L,
                                              float* __restrict__ out) {
    const int g0 = blockIdx.x * 512 + threadIdx.x;
    #pragma unroll
    for (int it = 0; it < 2; ++it) {
        const int g = g0 + it * 256;             // float4 index, 0..524287
        const size_t flat = (size_t)g * 4;
        const int row = (int)(flat >> 7);        // 0..16383
        const float l = L[row] + L[16384 + row];
        const float inv = (l > 0.f) ? 1.f / l : 0.f;
        const float4 p0 = *reinterpret_cast<const float4*>(&P[flat]);
        const float4 p1 = *reinterpret_cast<const float4*>(&P[2097152 + flat]);
        *reinterpret_cast<float4*>(&out[flat]) =
            make_float4((p0.x + p1.x) * inv, (p0.y + p1.y) * inv,
                        (p0.z + p1.z) * inv, (p0.w + p1.w) * inv);
    }
}

extern "C" void kernel_launch(void* const* d_in, const int* in_sizes, int n_in,
                              void* d_out, int out_size, void* d_ws, size_t ws_size,
                              hipStream_t stream) {
    const float* x     = (const float*)d_in[0];
    const int*   adj   = (const int*)d_in[1];
    const float* W     = (const float*)d_in[2];
    const float* a_src = (const float*)d_in[3];
    const float* a_dst = (const float*)d_in[4];
    float* out = (float*)d_out;

    unsigned short* hF    = (unsigned short*)d_ws;        // 4 MB
    unsigned short* Wf_hi = hF + 2097152;                 // 32 KB
    unsigned short* Wf_lo = Wf_hi + 16384;                // 32 KB
    float* Eg  = (float*)(Wf_lo + 16384);                 // 64 KB
    float* E2g = Eg + 16384;                              // 64 KB
    float* Sg  = E2g + 16384;                             // 64 KB
    float* S2g = Sg + 16384;                              // 64 KB
    unsigned* amT = (unsigned*)(S2g + 16384);             // 512 KB
    float* P = (float*)(amT + 131072);                    // 16 MB  [2][8][2048][128]
    float* L = P + 4194304;                               // 128 KB [2][8][2048]

    k_prep<<<520, 256, 0, stream>>>(adj, W, Wf_hi, Wf_lo, amT);
    k_h<<<1024, 256, 0, stream>>>(x, Wf_hi, Wf_lo, a_src, a_dst, hF, Eg, E2g, Sg, S2g);
    k_attn<<<dim3(32, BATCH, 2), 512, 0, stream>>>(hF, amT, Eg, E2g, Sg, S2g, P, L);
    k_comb<<<1024, 256, 0, stream>>>(P, L, out);
}